// Round 2
// baseline (183.056 us; speedup 1.0000x reference)
//
#include <hip/hip_runtime.h>
#include <math.h>

#define IMG 512
#define TW  32
#define TH  32
#define HR  42        // TH + 10 haloed rows
#define RS  48        // raw tile stride (floats), staged from c0-8, 12 float4
#define HS  36        // hb stride (floats), 16B-aligned groups
#define NPIX 12582912.0  // 48*512*512

// Normalized 11-tap Gaussian, sigma=1.5 — inline literals (no const-mem loads)
constexpr float G[11] = {
    0.00102838f, 0.00759876f, 0.03600077f, 0.10936069f, 0.21300554f,
    0.26601173f,
    0.21300554f, 0.10936069f, 0.03600077f, 0.00759876f, 0.00102838f};

__global__ __launch_bounds__(256) void ssim_tile_kernel(
    const float* __restrict__ x, const float* __restrict__ y,
    double* __restrict__ acc)
{
    __shared__ float sx[HR][RS];       // 8.06 KB
    __shared__ float sy[HR][RS];       // 8.06 KB
    __shared__ float hb[5][HR][HS];    // 30.2 KB
    __shared__ float wsum[4];

    const int tid = threadIdx.x;
    const int bx = blockIdx.x, by = blockIdx.y;
    const int c0 = bx * TW, r0 = by * TH;
    const size_t ioff = (size_t)blockIdx.z * IMG * IMG;
    const float* __restrict__ xb = x + ioff;
    const float* __restrict__ yb = y + ioff;

    // ---- stage 42 rows x 48 cols of x,y as float4 (zero-pad at borders) ----
    const bool interior = (bx > 0) & (bx < 15) & (by > 0) & (by < 15);
    if (interior) {
#pragma unroll
        for (int f = 0; f < 2; ++f) {
            int idx = tid + f * 256;
            if (idx < 504) {                 // 42 rows * 12 float4
                int rr = idx / 12, c4 = idx - rr * 12;
                int go = (r0 - 5 + rr) * IMG + (c0 - 8 + c4 * 4);
                *(float4*)&sx[rr][c4 * 4] = *(const float4*)(xb + go);
                *(float4*)&sy[rr][c4 * 4] = *(const float4*)(yb + go);
            }
        }
    } else {
#pragma unroll
        for (int f = 0; f < 2; ++f) {
            int idx = tid + f * 256;
            if (idx < 504) {
                int rr = idx / 12, c4 = idx - rr * 12;
                int gr = r0 - 5 + rr;
                bool rok = ((unsigned)gr < IMG);
                float vx[4], vy[4];
#pragma unroll
                for (int e = 0; e < 4; ++e) {
                    int gc = c0 - 8 + c4 * 4 + e;
                    bool ok = rok && ((unsigned)gc < IMG);
                    int gi = gr * IMG + gc;
                    vx[e] = ok ? xb[gi] : 0.f;
                    vy[e] = ok ? yb[gi] : 0.f;
                }
                *(float4*)&sx[rr][c4 * 4] = make_float4(vx[0], vx[1], vx[2], vx[3]);
                *(float4*)&sy[rr][c4 * 4] = make_float4(vy[0], vy[1], vy[2], vy[3]);
            }
        }
    }
    __syncthreads();

    // ---- horizontal pass: 42 rows x 8 col-groups = 336 tasks, 4 houts each ----
    auto htask = [&](int t) {
        int row = t >> 3;
        int g = t & 7;                        // output cols 4g..4g+3
        float wx[20], wy[20];
#pragma unroll
        for (int i = 0; i < 5; ++i) {         // 5 aligned float4 windows
            float4 fx = *(const float4*)&sx[row][4 * (g + i)];
            float4 fy = *(const float4*)&sy[row][4 * (g + i)];
            wx[4*i+0] = fx.x; wx[4*i+1] = fx.y; wx[4*i+2] = fx.z; wx[4*i+3] = fx.w;
            wy[4*i+0] = fy.x; wy[4*i+1] = fy.y; wy[4*i+2] = fy.z; wy[4*i+3] = fy.w;
        }
        float pxx[14], pyy[14], pxy[14];      // shared products, staged cols 3..16
#pragma unroll
        for (int j = 0; j < 14; ++j) {
            float a = wx[j + 3], b = wy[j + 3];
            pxx[j] = a * a; pyy[j] = b * b; pxy[j] = a * b;
        }
        float ax[4] = {}, ay[4] = {}, axx[4] = {}, ayy[4] = {}, axy[4] = {};
#pragma unroll
        for (int e = 0; e < 4; ++e)
#pragma unroll
            for (int k = 0; k < 11; ++k) {
                int j = e + k;                // product idx; raw idx j+3
                ax[e]  = fmaf(G[k], wx[j + 3], ax[e]);
                ay[e]  = fmaf(G[k], wy[j + 3], ay[e]);
                axx[e] = fmaf(G[k], pxx[j], axx[e]);
                ayy[e] = fmaf(G[k], pyy[j], ayy[e]);
                axy[e] = fmaf(G[k], pxy[j], axy[e]);
            }
        *(float4*)&hb[0][row][4 * g] = make_float4(ax[0], ax[1], ax[2], ax[3]);
        *(float4*)&hb[1][row][4 * g] = make_float4(ay[0], ay[1], ay[2], ay[3]);
        *(float4*)&hb[2][row][4 * g] = make_float4(axx[0], axx[1], axx[2], axx[3]);
        *(float4*)&hb[3][row][4 * g] = make_float4(ayy[0], ayy[1], ayy[2], ayy[3]);
        *(float4*)&hb[4][row][4 * g] = make_float4(axy[0], axy[1], axy[2], axy[3]);
    };
    htask(tid);
    if (tid < 80) htask(256 + tid);           // tasks 256..335
    __syncthreads();

    // ---- vertical pass: thread = (tx, ty), 4 rows ty*4..ty*4+3, col tx ----
    const int tx = tid & 31, ty = tid >> 5;
    const int rb = ty * 4;
    float vr[5][4] = {};
#pragma unroll
    for (int q = 0; q < 5; ++q) {
#pragma unroll
        for (int k = 0; k < 14; ++k) {
            float v = hb[q][rb + k][tx];      // single base + imm offsets
#pragma unroll
            for (int j = 0; j < 4; ++j) {
                if (k - j >= 0 && k - j <= 10)
                    vr[q][j] = fmaf(G[k - j], v, vr[q][j]);
            }
        }
    }

    // ---- pointwise SSIM + reduction ----
    float lsum = 0.f;
#pragma unroll
    for (int j = 0; j < 4; ++j) {
        float mx = vr[0][j], my = vr[1][j];
        float mxx = vr[2][j], myy = vr[3][j], mxy = vr[4][j];
        float mx2 = mx * mx, my2 = my * my, mxmy = mx * my;
        float num = (2.f * mxmy + 0.0001f) * (2.f * (mxy - mxmy) + 0.0009f);
        float den = (mx2 + my2 + 0.0001f) * ((mxx - mx2) + (myy - my2) + 0.0009f);
        lsum += num * __builtin_amdgcn_rcpf(den);
    }
#pragma unroll
    for (int off = 32; off > 0; off >>= 1)
        lsum += __shfl_down(lsum, off, 64);
    if ((tid & 63) == 0) wsum[tid >> 6] = lsum;
    __syncthreads();
    if (tid == 0)
        atomicAdd(acc, (double)(wsum[0] + wsum[1] + wsum[2] + wsum[3]));
}

__global__ void ssim_finalize_kernel(const double* __restrict__ acc,
                                     float* __restrict__ out)
{
    double mean = acc[0] / NPIX;
    out[0] = (float)(-log10(mean));  // loss
    out[1] = (float)mean;            // ssim_mean
}

extern "C" void kernel_launch(void* const* d_in, const int* in_sizes, int n_in,
                              void* d_out, int out_size, void* d_ws, size_t ws_size,
                              hipStream_t stream)
{
    const float* x = (const float*)d_in[0];
    const float* y = (const float*)d_in[1];
    float* out     = (float*)d_out;
    double* acc    = (double*)d_ws;

    hipMemsetAsync(acc, 0, sizeof(double), stream);

    dim3 grid(IMG / TW, IMG / TH, 48);
    ssim_tile_kernel<<<grid, 256, 0, stream>>>(x, y, acc);
    ssim_finalize_kernel<<<1, 1, 0, stream>>>(acc, out);
}

// Round 3
// 103.027 us; speedup vs baseline: 1.7768x; 1.7768x over previous
//
#include <hip/hip_runtime.h>
#include <math.h>

#define IMG  512
#define TW   32
#define TH   64
#define EXTR 74          // TH + 10 haloed rows
#define HS   33          // hb stride (floats): conflict-free for all patterns
#define NPIX 12582912.0  // 48*512*512

// Normalized 11-tap Gaussian, sigma=1.5 — inline literals
constexpr float G[11] = {
    0.00102838f, 0.00759876f, 0.03600077f, 0.10936069f, 0.21300554f,
    0.26601173f,
    0.21300554f, 0.10936069f, 0.03600077f, 0.00759876f, 0.00102838f};

__global__ __launch_bounds__(512) void ssim_tile_kernel(
    const float* __restrict__ x, const float* __restrict__ y,
    double* __restrict__ acc)
{
    __shared__ float hb[5][EXTR][HS];   // 48.84 KB -> 3 blocks/CU
    __shared__ float wsum[8];

    const int tid = threadIdx.x;
    const int bx = blockIdx.x, by = blockIdx.y;
    const int c0 = bx * TW, r0 = by * TH;
    const size_t ioff = (size_t)blockIdx.z * IMG * IMG;
    const float* __restrict__ xb = x + ioff;
    const float* __restrict__ yb = y + ioff;

    // rows needed: r0-5 .. r0+TH+4 ; cols needed: c0-8 .. c0+39
    const bool interior = (bx > 0) & (bx < 15) & (by > 0) & (by < 7);

    // ---- horizontal pass task: 4 outputs at row, cols 4g..4g+3 ----
    // reads 5 aligned float4 windows of x,y straight from global (L1-cached
    // overlap), writes 20 scalar b32 to hb (<=2-way bank alias = free)
    auto htask = [&](int t) {
        const int row = t >> 3;         // 0..73
        const int g   = t & 7;          // col group
        const int gr  = r0 - 5 + row;
        const int gc0 = c0 - 8 + 4 * g; // first of 20 raw cols
        float wx[20], wy[20];
        if (interior) {
            const float* __restrict__ px = xb + gr * IMG + gc0;
            const float* __restrict__ py = yb + gr * IMG + gc0;
#pragma unroll
            for (int i = 0; i < 5; ++i) {
                float4 fx = *(const float4*)(px + 4 * i);
                float4 fy = *(const float4*)(py + 4 * i);
                wx[4*i+0] = fx.x; wx[4*i+1] = fx.y; wx[4*i+2] = fx.z; wx[4*i+3] = fx.w;
                wy[4*i+0] = fy.x; wy[4*i+1] = fy.y; wy[4*i+2] = fy.z; wy[4*i+3] = fy.w;
            }
        } else {
            const bool rok = ((unsigned)gr < IMG);
            const float* __restrict__ px = xb + gr * IMG;
            const float* __restrict__ py = yb + gr * IMG;
#pragma unroll
            for (int i = 0; i < 5; ++i) {
                int gc = gc0 + 4 * i;
                if (rok && gc >= 0 && gc + 3 < IMG) {
                    float4 fx = *(const float4*)(px + gc);
                    float4 fy = *(const float4*)(py + gc);
                    wx[4*i+0] = fx.x; wx[4*i+1] = fx.y; wx[4*i+2] = fx.z; wx[4*i+3] = fx.w;
                    wy[4*i+0] = fy.x; wy[4*i+1] = fy.y; wy[4*i+2] = fy.z; wy[4*i+3] = fy.w;
                } else {
#pragma unroll
                    for (int e = 0; e < 4; ++e) {
                        int c = gc + e;
                        bool ok = rok && ((unsigned)c < IMG);
                        wx[4*i+e] = ok ? px[c] : 0.f;
                        wy[4*i+e] = ok ? py[c] : 0.f;
                    }
                }
            }
        }
        // shared products for raw cols 3..16 (all that the 4 outputs touch)
        float pxx[14], pyy[14], pxy[14];
#pragma unroll
        for (int j = 0; j < 14; ++j) {
            float a = wx[j + 3], b = wy[j + 3];
            pxx[j] = a * a; pyy[j] = b * b; pxy[j] = a * b;
        }
        float ax[4] = {}, ay[4] = {}, axx[4] = {}, ayy[4] = {}, axy[4] = {};
#pragma unroll
        for (int e = 0; e < 4; ++e)
#pragma unroll
            for (int k = 0; k < 11; ++k) {
                ax[e]  = fmaf(G[k], wx[e + k + 3], ax[e]);
                ay[e]  = fmaf(G[k], wy[e + k + 3], ay[e]);
                axx[e] = fmaf(G[k], pxx[e + k], axx[e]);
                ayy[e] = fmaf(G[k], pyy[e + k], ayy[e]);
                axy[e] = fmaf(G[k], pxy[e + k], axy[e]);
            }
#pragma unroll
        for (int e = 0; e < 4; ++e) {
            int cc = 4 * g + e;
            hb[0][row][cc] = ax[e];
            hb[1][row][cc] = ay[e];
            hb[2][row][cc] = axx[e];
            hb[3][row][cc] = ayy[e];
            hb[4][row][cc] = axy[e];
        }
    };

    htask(tid);                         // tasks 0..511
    if (tid < EXTR * 8 - 512)           // tasks 512..591 (80 extra)
        htask(512 + tid);
    __syncthreads();

    // ---- vertical pass: thread = col tx, 4 rows rb..rb+3 ----
    const int tx = tid & 31;
    const int rb = (tid >> 5) * 4;      // 0,4,...,60
    float vr[5][4] = {};
#pragma unroll
    for (int q = 0; q < 5; ++q) {
#pragma unroll
        for (int k = 0; k < 14; ++k) {
            float v = hb[q][rb + k][tx];
#pragma unroll
            for (int j = 0; j < 4; ++j) {
                if (k - j >= 0 && k - j <= 10)
                    vr[q][j] = fmaf(G[k - j], v, vr[q][j]);
            }
        }
    }

    // ---- pointwise SSIM + block reduction ----
    float lsum = 0.f;
#pragma unroll
    for (int j = 0; j < 4; ++j) {
        float mx = vr[0][j], my = vr[1][j];
        float mxx = vr[2][j], myy = vr[3][j], mxy = vr[4][j];
        float mx2 = mx * mx, my2 = my * my, mxmy = mx * my;
        float num = (2.f * mxmy + 0.0001f) * (2.f * (mxy - mxmy) + 0.0009f);
        float den = (mx2 + my2 + 0.0001f) * ((mxx - mx2) + (myy - my2) + 0.0009f);
        lsum += num * __builtin_amdgcn_rcpf(den);
    }
#pragma unroll
    for (int off = 32; off > 0; off >>= 1)
        lsum += __shfl_down(lsum, off, 64);
    if ((tid & 63) == 0) wsum[tid >> 6] = lsum;
    __syncthreads();
    if (tid == 0) {
        float s = 0.f;
#pragma unroll
        for (int w = 0; w < 8; ++w) s += wsum[w];
        atomicAdd(acc, (double)s);
    }
}

__global__ void ssim_finalize_kernel(const double* __restrict__ acc,
                                     float* __restrict__ out)
{
    double mean = acc[0] / NPIX;
    out[0] = (float)(-log10(mean));  // loss
    out[1] = (float)mean;            // ssim_mean
}

extern "C" void kernel_launch(void* const* d_in, const int* in_sizes, int n_in,
                              void* d_out, int out_size, void* d_ws, size_t ws_size,
                              hipStream_t stream)
{
    const float* x = (const float*)d_in[0];
    const float* y = (const float*)d_in[1];
    float* out     = (float*)d_out;
    double* acc    = (double*)d_ws;

    hipMemsetAsync(acc, 0, sizeof(double), stream);

    dim3 grid(IMG / TW, IMG / TH, 48);   // 16 x 8 x 48 = 6144 blocks
    ssim_tile_kernel<<<grid, 512, 0, stream>>>(x, y, acc);
    ssim_finalize_kernel<<<1, 1, 0, stream>>>(acc, out);
}